// Round 1
// baseline (608.991 us; speedup 1.0000x reference)
//
#include <hip/hip_runtime.h>
#include <stdint.h>

typedef unsigned short ushort_t;
typedef __bf16 bf16x8 __attribute__((ext_vector_type(8)));
typedef float f32x4 __attribute__((ext_vector_type(4)));

#define T_TOK 8192
#define HDIM  1024
#define EXP   8
#define FDIM  2048
#define CAP   1280

// fp32 -> bf16 round-to-nearest-even (bit level, deterministic)
__device__ __forceinline__ unsigned short f2b(float f) {
  unsigned u = __float_as_uint(f);
  u = (u + 0x7fffu + ((u >> 16) & 1u)) >> 16;
  return (unsigned short)u;
}

__device__ __forceinline__ unsigned pk2(unsigned short lo, unsigned short hi) {
  return (unsigned)lo | ((unsigned)hi << 16);
}

// async global->LDS, 16B per lane. LDS dest must be wave-uniform base + lane*16.
__device__ __forceinline__ void gl_lds16(const void* g, void* l) {
  __builtin_amdgcn_global_load_lds((__attribute__((address_space(1))) void*)g,
                                   (__attribute__((address_space(3))) void*)l,
                                   16, 0, 0);
}

// ---------------------------------------------------------------- gating GEMV
// one wave per token: logits[t][e] = sum_h x[t][h] * gw[h][e]   (fp32 exact-ish)
__global__ void __launch_bounds__(256) gate_logits_k(
    const float* __restrict__ x, const float* __restrict__ gw,
    float* __restrict__ logits)
{
  int wave = threadIdx.x >> 6, lane = threadIdx.x & 63;
  int t = blockIdx.x * 4 + wave;
  const float* xr = x + (size_t)t * HDIM;
  float acc[8];
#pragma unroll
  for (int i = 0; i < 8; ++i) acc[i] = 0.f;
#pragma unroll
  for (int i = 0; i < 16; ++i) {
    int h = i * 64 + lane;
    float xv = xr[h];
    const float4* g4 = (const float4*)(gw + (size_t)h * EXP);
    float4 lo = g4[0], hi = g4[1];
    acc[0] += xv * lo.x; acc[1] += xv * lo.y; acc[2] += xv * lo.z; acc[3] += xv * lo.w;
    acc[4] += xv * hi.x; acc[5] += xv * hi.y; acc[6] += xv * hi.z; acc[7] += xv * hi.w;
  }
#pragma unroll
  for (int off = 32; off > 0; off >>= 1) {
#pragma unroll
    for (int i = 0; i < 8; ++i) acc[i] += __shfl_xor(acc[i], off, 64);
  }
  if (lane == 0) {
#pragma unroll
    for (int i = 0; i < 8; ++i) logits[(size_t)t * EXP + i] = acc[i];
  }
}

// ------------------------------------------------------ per-expert top-k + softmax
__device__ __forceinline__ float unmap_f(unsigned m) {
  unsigned u = (m & 0x80000000u) ? (m ^ 0x80000000u) : ~m;
  return __uint_as_float(u);
}

// one block per expert; bitonic sort of 8192 u64 keys (mapped score | idx) in LDS
__global__ void __launch_bounds__(1024) topk_softmax_k(
    const float* __restrict__ logits, int* __restrict__ idxo, float* __restrict__ wgto)
{
  __shared__ unsigned long long keys[T_TOK];  // 64 KB
  int e = blockIdx.x;
  int tid = threadIdx.x;
  for (int i = tid; i < T_TOK; i += 1024) {
    unsigned u = __float_as_uint(logits[(size_t)i * EXP + e]);
    unsigned m = (u & 0x80000000u) ? ~u : (u | 0x80000000u);  // order-preserving map
    keys[i] = ((unsigned long long)m << 32) | (unsigned)i;
  }
  __syncthreads();
  for (int k = 2; k <= T_TOK; k <<= 1) {
    for (int j = k >> 1; j > 0; j >>= 1) {
      for (int p = tid; p < T_TOK / 2; p += 1024) {
        int i = ((p & ~(j - 1)) << 1) | (p & (j - 1));
        int ixj = i | j;
        unsigned long long a = keys[i], b = keys[ixj];
        bool desc = ((i & k) == 0);
        if ((a < b) == desc) { keys[i] = b; keys[ixj] = a; }
      }
      __syncthreads();
    }
  }
  // wave 0 finishes: softmax over top-CAP (sorted descending, max = keys[0])
  if (tid < 64) {
    float mx = unmap_f((unsigned)(keys[0] >> 32));
    float sum = 0.f;
    for (int c = tid; c < CAP; c += 64)
      sum += __expf(unmap_f((unsigned)(keys[c] >> 32)) - mx);
#pragma unroll
    for (int off = 32; off > 0; off >>= 1) sum += __shfl_xor(sum, off, 64);
    float inv = 1.f / sum;
    for (int c = tid; c < CAP; c += 64) {
      unsigned long long kk = keys[c];
      idxo[e * CAP + c] = (int)(kk & 0xffffffffull);
      wgto[e * CAP + c] = __expf(unmap_f((unsigned)(kk >> 32)) - mx) * inv;
    }
  }
}

// ---------------------------------------------------------------- x -> bf16 cast
__global__ void __launch_bounds__(256) cast_bf16_k(
    const float* __restrict__ x, ushort_t* __restrict__ xb)
{
  size_t base = ((size_t)blockIdx.x * 256 + threadIdx.x) * 8;
  float4 a = *(const float4*)(x + base);
  float4 b = *(const float4*)(x + base + 4);
  uint4 v;
  v.x = pk2(f2b(a.x), f2b(a.y)); v.y = pk2(f2b(a.z), f2b(a.w));
  v.z = pk2(f2b(b.x), f2b(b.y)); v.w = pk2(f2b(b.z), f2b(b.w));
  *(uint4*)(xb + base) = v;
}

// ------------------------------------------- weight transpose + cast (LDS tiled)
// in: [E][R][Cc] fp32   out: [E][Cc][R] bf16
__global__ void __launch_bounds__(256) transpose_cast_k(
    const float* __restrict__ in, ushort_t* __restrict__ out, int R, int Cc)
{
  __shared__ float tile[64][65];
  int tilesC = Cc >> 6;
  int tilesPer = (R >> 6) * tilesC;
  int b = blockIdx.x;
  int e = b / tilesPer;
  int tb = b - e * tilesPer;
  int rt = tb / tilesC, ct = tb - rt * tilesC;
  const float* src = in + (size_t)e * R * Cc;
  ushort_t* dst = out + (size_t)e * R * Cc;
  int tr = threadIdx.x >> 4, tc = threadIdx.x & 15;
#pragma unroll
  for (int it = 0; it < 4; ++it) {
    int r = (rt << 6) + (it << 4) + tr;
    int c = (ct << 6) + (tc << 2);
    float4 v = *(const float4*)(src + (size_t)r * Cc + c);
    tile[(it << 4) + tr][(tc << 2) + 0] = v.x;
    tile[(it << 4) + tr][(tc << 2) + 1] = v.y;
    tile[(it << 4) + tr][(tc << 2) + 2] = v.z;
    tile[(it << 4) + tr][(tc << 2) + 3] = v.w;
  }
  __syncthreads();
#pragma unroll
  for (int it = 0; it < 4; ++it) {
    int cl = (it << 4) + tr;   // output-row (Cc dim) within tile
    int rl = tc << 2;          // output-col (R dim) group of 4
    unsigned lo = pk2(f2b(tile[rl + 0][cl]), f2b(tile[rl + 1][cl]));
    unsigned hi = pk2(f2b(tile[rl + 2][cl]), f2b(tile[rl + 3][cl]));
    unsigned long long v = (unsigned long long)lo | ((unsigned long long)hi << 32);
    *(unsigned long long*)(dst + (size_t)((ct << 6) + cl) * R + (rt << 6) + rl) = v;
  }
}

// ------------------------------------------------- GEMM1: SwiGLU hidden (bf16 MFMA)
// A = gathered tokens (row-gather from xb via idx), B = w1t/w3t [E][F][H] (n-major,k-contig)
// out: hidden[E][CAP][FDIM] bf16
__global__ void __launch_bounds__(256) gemm1_swiglu_k(
    const ushort_t* __restrict__ xb,   // [T_TOK][HDIM]
    const ushort_t* __restrict__ w1t,  // [E][FDIM][HDIM]
    const ushort_t* __restrict__ w3t,
    const int* __restrict__ idx,       // [E][CAP]
    ushort_t* __restrict__ hidden)     // [E][CAP][FDIM]
{
  // block order: e(8) x ng(4) x mt(10) x ni(4); nt = ng*4+ni  (L2 reuse swizzle)
  int b = blockIdx.x;
  int ni_ = b & 3; int t1 = b >> 2; int mt = t1 % 10; int t2 = t1 / 10;
  int ng = t2 & 3; int e = t2 >> 2;
  int nt = ng * 4 + ni_;

  __shared__ __bf16 Alds[128 * 32];
  __shared__ __bf16 B1lds[128 * 32];
  __shared__ __bf16 B3lds[128 * 32];

  int tid = threadIdx.x;
  int lane = tid & 63, wave = tid >> 6;
  int wm = wave & 1, wn = wave >> 1;
  int l15 = lane & 15, quad = lane >> 4;

  // staging granules: g0=tid (rows 0..63), g1=tid+256 (rows 64..127); 16B each
  int r0 = tid >> 2, kc0 = tid & 3;
  int r1 = r0 + 64;
  const int* idxe = idx + e * CAP + mt * 128;
  const ushort_t* a0 = xb + (size_t)idxe[r0] * HDIM + kc0 * 8;
  const ushort_t* a1 = xb + (size_t)idxe[r1] * HDIM + kc0 * 8;
  const ushort_t* wb1 = w1t + ((size_t)e * FDIM + nt * 128) * HDIM;
  const ushort_t* wb3 = w3t + ((size_t)e * FDIM + nt * 128) * HDIM;
  const ushort_t* b10 = wb1 + (size_t)r0 * HDIM + kc0 * 8;
  const ushort_t* b11 = wb1 + (size_t)r1 * HDIM + kc0 * 8;
  const ushort_t* b30 = wb3 + (size_t)r0 * HDIM + kc0 * 8;
  const ushort_t* b31 = wb3 + (size_t)r1 * HDIM + kc0 * 8;

  f32x4 acc1[4][4];
  f32x4 acc3[4][4];
#pragma unroll
  for (int i = 0; i < 4; ++i)
#pragma unroll
    for (int j = 0; j < 4; ++j) {
      acc1[i][j] = (f32x4){0.f, 0.f, 0.f, 0.f};
      acc3[i][j] = (f32x4){0.f, 0.f, 0.f, 0.f};
    }

  for (int kt = 0; kt < HDIM / 32; ++kt) {
    gl_lds16(a0,  Alds  + (size_t)tid * 8);
    gl_lds16(a1,  Alds  + (size_t)(tid + 256) * 8);
    gl_lds16(b10, B1lds + (size_t)tid * 8);
    gl_lds16(b11, B1lds + (size_t)(tid + 256) * 8);
    gl_lds16(b30, B3lds + (size_t)tid * 8);
    gl_lds16(b31, B3lds + (size_t)(tid + 256) * 8);
    __syncthreads();

    bf16x8 af[4], bf1[4], bf3[4];
#pragma unroll
    for (int i = 0; i < 4; ++i) {
      af[i]  = *(const bf16x8*)(Alds  + ((wm * 64 + i * 16 + l15) * 32 + quad * 8));
      bf1[i] = *(const bf16x8*)(B1lds + ((wn * 64 + i * 16 + l15) * 32 + quad * 8));
      bf3[i] = *(const bf16x8*)(B3lds + ((wn * 64 + i * 16 + l15) * 32 + quad * 8));
    }
#pragma unroll
    for (int mi = 0; mi < 4; ++mi)
#pragma unroll
      for (int nj = 0; nj < 4; ++nj) {
        acc1[mi][nj] = __builtin_amdgcn_mfma_f32_16x16x32_bf16(af[mi], bf1[nj], acc1[mi][nj], 0, 0, 0);
        acc3[mi][nj] = __builtin_amdgcn_mfma_f32_16x16x32_bf16(af[mi], bf3[nj], acc3[mi][nj], 0, 0, 0);
      }
    __syncthreads();
    a0 += 32; a1 += 32; b10 += 32; b11 += 32; b30 += 32; b31 += 32;
  }

  // epilogue: hidden = silu(a1)*a3, bf16 store
  // C/D layout: col = lane&15, row = quad*4 + reg  [verified m89/m91]
  ushort_t* hb = hidden + ((size_t)e * CAP + mt * 128) * FDIM + nt * 128;
#pragma unroll
  for (int mi = 0; mi < 4; ++mi)
#pragma unroll
    for (int nj = 0; nj < 4; ++nj)
#pragma unroll
      for (int r = 0; r < 4; ++r) {
        int row = wm * 64 + mi * 16 + quad * 4 + r;
        int col = wn * 64 + nj * 16 + l15;
        float v1 = acc1[mi][nj][r];
        float v3 = acc3[mi][nj][r];
        float s = (v1 / (1.f + __expf(-v1))) * v3;
        hb[(size_t)row * FDIM + col] = f2b(s);
      }
}

// ------------------------------------- GEMM2: hidden @ w2 -> weighted scatter-add
__global__ void __launch_bounds__(256) gemm2_scatter_k(
    const ushort_t* __restrict__ hidden, // [E][CAP][FDIM]
    const ushort_t* __restrict__ w2t,    // [E][HDIM][FDIM]
    const int* __restrict__ idx,
    const float* __restrict__ wgt,
    float* __restrict__ y)               // [T_TOK][HDIM]
{
  // block order: e(8) x ng(2) x mt(10) x ni(4); nt = ng*4+ni
  int b = blockIdx.x;
  int ni_ = b & 3; int t1 = b >> 2; int mt = t1 % 10; int t2 = t1 / 10;
  int ng = t2 & 1; int e = t2 >> 1;
  int nt = ng * 4 + ni_;

  __shared__ __bf16 Alds[128 * 32];
  __shared__ __bf16 Blds[128 * 32];
  __shared__ int   idxs[128];
  __shared__ float wgts[128];

  int tid = threadIdx.x;
  int lane = tid & 63, wave = tid >> 6;
  int wm = wave & 1, wn = wave >> 1;
  int l15 = lane & 15, quad = lane >> 4;

  if (tid < 128) {
    idxs[tid] = idx[e * CAP + mt * 128 + tid];
    wgts[tid] = wgt[e * CAP + mt * 128 + tid];
  }

  int r0 = tid >> 2, kc0 = tid & 3;
  int r1 = r0 + 64;
  const ushort_t* a0 = hidden + ((size_t)e * CAP + mt * 128 + r0) * FDIM + kc0 * 8;
  const ushort_t* a1 = hidden + ((size_t)e * CAP + mt * 128 + r1) * FDIM + kc0 * 8;
  const ushort_t* b0 = w2t + ((size_t)e * HDIM + nt * 128 + r0) * FDIM + kc0 * 8;
  const ushort_t* b1 = w2t + ((size_t)e * HDIM + nt * 128 + r1) * FDIM + kc0 * 8;

  f32x4 acc[4][4];
#pragma unroll
  for (int i = 0; i < 4; ++i)
#pragma unroll
    for (int j = 0; j < 4; ++j) acc[i][j] = (f32x4){0.f, 0.f, 0.f, 0.f};

  for (int kt = 0; kt < FDIM / 32; ++kt) {
    gl_lds16(a0, Alds + (size_t)tid * 8);
    gl_lds16(a1, Alds + (size_t)(tid + 256) * 8);
    gl_lds16(b0, Blds + (size_t)tid * 8);
    gl_lds16(b1, Blds + (size_t)(tid + 256) * 8);
    __syncthreads();

    bf16x8 af[4], bf[4];
#pragma unroll
    for (int i = 0; i < 4; ++i) {
      af[i] = *(const bf16x8*)(Alds + ((wm * 64 + i * 16 + l15) * 32 + quad * 8));
      bf[i] = *(const bf16x8*)(Blds + ((wn * 64 + i * 16 + l15) * 32 + quad * 8));
    }
#pragma unroll
    for (int mi = 0; mi < 4; ++mi)
#pragma unroll
      for (int nj = 0; nj < 4; ++nj)
        acc[mi][nj] = __builtin_amdgcn_mfma_f32_16x16x32_bf16(af[mi], bf[nj], acc[mi][nj], 0, 0, 0);
    __syncthreads();
    a0 += 32; a1 += 32; b0 += 32; b1 += 32;
  }

#pragma unroll
  for (int mi = 0; mi < 4; ++mi)
#pragma unroll
    for (int nj = 0; nj < 4; ++nj)
#pragma unroll
      for (int r = 0; r < 4; ++r) {
        int row = wm * 64 + mi * 16 + quad * 4 + r;
        int col = nt * 128 + wn * 64 + nj * 16 + l15;
        float v = acc[mi][nj][r] * wgts[row];
        atomicAdd(y + (size_t)idxs[row] * HDIM + col, v);
      }
}

// --------------------------------------------------------------------- launch
extern "C" void kernel_launch(void* const* d_in, const int* in_sizes, int n_in,
                              void* d_out, int out_size, void* d_ws, size_t ws_size,
                              hipStream_t stream)
{
  const float* x  = (const float*)d_in[0];
  const float* gw = (const float*)d_in[1];
  const float* w1 = (const float*)d_in[2];
  const float* w2 = (const float*)d_in[3];   // NOTE: dict order is x,gate_w,w1,w2,w3
  const float* w3 = (const float*)d_in[4];
  float* y = (float*)d_out;

  char* ws = (char*)d_ws;
  float*    logits = (float*)(ws + 0x0);        // 256 KB
  int*      idx    = (int*)(ws + 0x40000);      // 40 KB
  float*    wgt    = (float*)(ws + 0x4A000);    // 40 KB
  ushort_t* xb     = (ushort_t*)(ws + 0x54000);    // 16 MB  [T][H] bf16
  ushort_t* w1t    = (ushort_t*)(ws + 0x1054000);  // 32 MB  [E][F][H]
  ushort_t* w3t    = (ushort_t*)(ws + 0x3054000);  // 32 MB
  ushort_t* w2t    = (ushort_t*)(ws + 0x5054000);  // 32 MB  [E][H][F]
  ushort_t* hid    = (ushort_t*)(ws + 0x7054000);  // 40 MB  [E][CAP][F]

  hipMemsetAsync(d_out, 0, (size_t)out_size * sizeof(float), stream);
  gate_logits_k<<<T_TOK / 4, 256, 0, stream>>>(x, gw, logits);
  topk_softmax_k<<<EXP, 1024, 0, stream>>>(logits, idx, wgt);
  cast_bf16_k<<<T_TOK * HDIM / (256 * 8), 256, 0, stream>>>(x, xb);
  transpose_cast_k<<<EXP * (HDIM / 64) * (FDIM / 64), 256, 0, stream>>>(w1, w1t, HDIM, FDIM);
  transpose_cast_k<<<EXP * (HDIM / 64) * (FDIM / 64), 256, 0, stream>>>(w3, w3t, HDIM, FDIM);
  transpose_cast_k<<<EXP * (FDIM / 64) * (HDIM / 64), 256, 0, stream>>>(w2, w2t, FDIM, HDIM);
  gemm1_swiglu_k<<<EXP * 4 * 10 * 4, 256, 0, stream>>>(xb, w1t, w3t, idx, hid);
  gemm2_scatter_k<<<EXP * 2 * 10 * 4, 256, 0, stream>>>(hid, w2t, idx, wgt, y);
}

// Round 2
// 572.753 us; speedup vs baseline: 1.0633x; 1.0633x over previous
//
#include <hip/hip_runtime.h>
#include <stdint.h>

typedef unsigned short ushort_t;
typedef __bf16 bf16x8 __attribute__((ext_vector_type(8)));
typedef float f32x4 __attribute__((ext_vector_type(4)));

#define T_TOK 8192
#define HDIM  1024
#define EXP   8
#define FDIM  2048
#define CAP   1280

// fp32 -> bf16 round-to-nearest-even (bit level, deterministic)
__device__ __forceinline__ unsigned short f2b(float f) {
  unsigned u = __float_as_uint(f);
  u = (u + 0x7fffu + ((u >> 16) & 1u)) >> 16;
  return (unsigned short)u;
}

__device__ __forceinline__ unsigned pk2(unsigned short lo, unsigned short hi) {
  return (unsigned)lo | ((unsigned)hi << 16);
}

// async global->LDS, 16B per lane. LDS dest must be wave-uniform base + lane*16.
__device__ __forceinline__ void gl_lds16(const void* g, void* l) {
  __builtin_amdgcn_global_load_lds((__attribute__((address_space(1))) void*)g,
                                   (__attribute__((address_space(3))) void*)l,
                                   16, 0, 0);
}

// ---------------------------------------------------------------- gating GEMV
__global__ void __launch_bounds__(256) gate_logits_k(
    const float* __restrict__ x, const float* __restrict__ gw,
    float* __restrict__ logits)
{
  int wave = threadIdx.x >> 6, lane = threadIdx.x & 63;
  int t = blockIdx.x * 4 + wave;
  const float* xr = x + (size_t)t * HDIM;
  float acc[8];
#pragma unroll
  for (int i = 0; i < 8; ++i) acc[i] = 0.f;
#pragma unroll
  for (int i = 0; i < 16; ++i) {
    int h = i * 64 + lane;
    float xv = xr[h];
    const float4* g4 = (const float4*)(gw + (size_t)h * EXP);
    float4 lo = g4[0], hi = g4[1];
    acc[0] += xv * lo.x; acc[1] += xv * lo.y; acc[2] += xv * lo.z; acc[3] += xv * lo.w;
    acc[4] += xv * hi.x; acc[5] += xv * hi.y; acc[6] += xv * hi.z; acc[7] += xv * hi.w;
  }
#pragma unroll
  for (int off = 32; off > 0; off >>= 1) {
#pragma unroll
    for (int i = 0; i < 8; ++i) acc[i] += __shfl_xor(acc[i], off, 64);
  }
  if (lane == 0) {
#pragma unroll
    for (int i = 0; i < 8; ++i) logits[(size_t)t * EXP + i] = acc[i];
  }
}

// ------------------------------------------------------ per-expert top-k + softmax
__device__ __forceinline__ float unmap_f(unsigned m) {
  unsigned u = (m & 0x80000000u) ? (m ^ 0x80000000u) : ~m;
  return __uint_as_float(u);
}

__global__ void __launch_bounds__(1024) topk_softmax_k(
    const float* __restrict__ logits, int* __restrict__ idxo, float* __restrict__ wgto)
{
  __shared__ unsigned long long keys[T_TOK];  // 64 KB
  int e = blockIdx.x;
  int tid = threadIdx.x;
  for (int i = tid; i < T_TOK; i += 1024) {
    unsigned u = __float_as_uint(logits[(size_t)i * EXP + e]);
    unsigned m = (u & 0x80000000u) ? ~u : (u | 0x80000000u);  // order-preserving map
    keys[i] = ((unsigned long long)m << 32) | (unsigned)i;
  }
  __syncthreads();
  for (int k = 2; k <= T_TOK; k <<= 1) {
    for (int j = k >> 1; j > 0; j >>= 1) {
      for (int p = tid; p < T_TOK / 2; p += 1024) {
        int i = ((p & ~(j - 1)) << 1) | (p & (j - 1));
        int ixj = i | j;
        unsigned long long a = keys[i], b = keys[ixj];
        bool desc = ((i & k) == 0);
        if ((a < b) == desc) { keys[i] = b; keys[ixj] = a; }
      }
      __syncthreads();
    }
  }
  if (tid < 64) {
    float mx = unmap_f((unsigned)(keys[0] >> 32));
    float sum = 0.f;
    for (int c = tid; c < CAP; c += 64)
      sum += __expf(unmap_f((unsigned)(keys[c] >> 32)) - mx);
#pragma unroll
    for (int off = 32; off > 0; off >>= 1) sum += __shfl_xor(sum, off, 64);
    float inv = 1.f / sum;
    for (int c = tid; c < CAP; c += 64) {
      unsigned long long kk = keys[c];
      idxo[e * CAP + c] = (int)(kk & 0xffffffffull);
      wgto[e * CAP + c] = __expf(unmap_f((unsigned)(kk >> 32)) - mx) * inv;
    }
  }
}

// ---------------------------------------------------------------- x -> bf16 cast
__global__ void __launch_bounds__(256) cast_bf16_k(
    const float* __restrict__ x, ushort_t* __restrict__ xb)
{
  size_t base = ((size_t)blockIdx.x * 256 + threadIdx.x) * 8;
  float4 a = *(const float4*)(x + base);
  float4 b = *(const float4*)(x + base + 4);
  uint4 v;
  v.x = pk2(f2b(a.x), f2b(a.y)); v.y = pk2(f2b(a.z), f2b(a.w));
  v.z = pk2(f2b(b.x), f2b(b.y)); v.w = pk2(f2b(b.z), f2b(b.w));
  *(uint4*)(xb + base) = v;
}

// ------------------------------------------- weight transpose + cast (LDS tiled)
// in: [E][R][Cc] fp32   out: [E][Cc][R] bf16
__global__ void __launch_bounds__(256) transpose_cast_k(
    const float* __restrict__ in, ushort_t* __restrict__ out, int R, int Cc)
{
  __shared__ float tile[64][65];
  int tilesC = Cc >> 6;
  int tilesPer = (R >> 6) * tilesC;
  int b = blockIdx.x;
  int e = b / tilesPer;
  int tb = b - e * tilesPer;
  int rt = tb / tilesC, ct = tb - rt * tilesC;
  const float* src = in + (size_t)e * R * Cc;
  ushort_t* dst = out + (size_t)e * R * Cc;
  int tr = threadIdx.x >> 4, tc = threadIdx.x & 15;
#pragma unroll
  for (int it = 0; it < 4; ++it) {
    int r = (rt << 6) + (it << 4) + tr;
    int c = (ct << 6) + (tc << 2);
    float4 v = *(const float4*)(src + (size_t)r * Cc + c);
    tile[(it << 4) + tr][(tc << 2) + 0] = v.x;
    tile[(it << 4) + tr][(tc << 2) + 1] = v.y;
    tile[(it << 4) + tr][(tc << 2) + 2] = v.z;
    tile[(it << 4) + tr][(tc << 2) + 3] = v.w;
  }
  __syncthreads();
#pragma unroll
  for (int it = 0; it < 4; ++it) {
    int cl = (it << 4) + tr;
    int rl = tc << 2;
    unsigned lo = pk2(f2b(tile[rl + 0][cl]), f2b(tile[rl + 1][cl]));
    unsigned hi = pk2(f2b(tile[rl + 2][cl]), f2b(tile[rl + 3][cl]));
    unsigned long long v = (unsigned long long)lo | ((unsigned long long)hi << 32);
    *(unsigned long long*)(dst + (size_t)((ct << 6) + cl) * R + (rt << 6) + rl) = v;
  }
}

// ------------------------------------------------- GEMM1: SwiGLU hidden (bf16 MFMA)
// 128x64 block tile, dual accumulator (X.W1, X.W3), fused SiLU*mul epilogue.
// acc = 64 AGPRs/wave -> VGPR+AGPR ~228 -> 2 waves/SIMD (vs 292 -> 1 in round 1).
__global__ void __launch_bounds__(256) gemm1_swiglu_k(
    const ushort_t* __restrict__ xb,   // [T_TOK][HDIM]
    const ushort_t* __restrict__ w1t,  // [E][FDIM][HDIM]
    const ushort_t* __restrict__ w3t,
    const int* __restrict__ idx,       // [E][CAP]
    ushort_t* __restrict__ hidden)     // [E][CAP][FDIM]
{
  // b = ((e*4 + ng)*10 + mt)*8 + ni ; nt = ng*8+ni (64-wide n-tiles, groups of 8 for L2)
  int b = blockIdx.x;
  int ni_ = b & 7; int t1 = b >> 3; int mt = t1 % 10; int t2 = t1 / 10;
  int ng = t2 & 3; int e = t2 >> 2;
  int nt = ng * 8 + ni_;             // 0..31

  __shared__ __bf16 Alds[128 * 32];  // 8 KB
  __shared__ __bf16 B1lds[64 * 32];  // 4 KB
  __shared__ __bf16 B3lds[64 * 32];  // 4 KB

  int tid = threadIdx.x;
  int lane = tid & 63, wave = tid >> 6;
  int wm = wave & 1, wn = wave >> 1;     // m-split 2 x n-split 2
  int l15 = lane & 15, quad = lane >> 4;

  int r0 = tid >> 2, kc0 = tid & 3;      // A granule 0: rows 0..63
  int r1 = r0 + 64;                      // A granule 1: rows 64..127
  const int* idxe = idx + e * CAP + mt * 128;
  const ushort_t* a0 = xb + (size_t)idxe[r0] * HDIM + kc0 * 8;
  const ushort_t* a1 = xb + (size_t)idxe[r1] * HDIM + kc0 * 8;
  const ushort_t* wb1 = w1t + ((size_t)e * FDIM + nt * 64) * HDIM;
  const ushort_t* wb3 = w3t + ((size_t)e * FDIM + nt * 64) * HDIM;
  const ushort_t* b1p = wb1 + (size_t)r0 * HDIM + kc0 * 8;   // one granule each
  const ushort_t* b3p = wb3 + (size_t)r0 * HDIM + kc0 * 8;

  f32x4 acc1[4][2];
  f32x4 acc3[4][2];
#pragma unroll
  for (int i = 0; i < 4; ++i)
#pragma unroll
    for (int j = 0; j < 2; ++j) {
      acc1[i][j] = (f32x4){0.f, 0.f, 0.f, 0.f};
      acc3[i][j] = (f32x4){0.f, 0.f, 0.f, 0.f};
    }

  for (int kt = 0; kt < HDIM / 32; ++kt) {
    gl_lds16(a0,  Alds  + (size_t)tid * 8);
    gl_lds16(a1,  Alds  + (size_t)(tid + 256) * 8);
    gl_lds16(b1p, B1lds + (size_t)tid * 8);
    gl_lds16(b3p, B3lds + (size_t)tid * 8);
    __syncthreads();

    bf16x8 af[4], bf1[2], bf3[2];
#pragma unroll
    for (int i = 0; i < 4; ++i)
      af[i]  = *(const bf16x8*)(Alds  + ((wm * 64 + i * 16 + l15) * 32 + quad * 8));
#pragma unroll
    for (int j = 0; j < 2; ++j) {
      bf1[j] = *(const bf16x8*)(B1lds + ((wn * 32 + j * 16 + l15) * 32 + quad * 8));
      bf3[j] = *(const bf16x8*)(B3lds + ((wn * 32 + j * 16 + l15) * 32 + quad * 8));
    }
#pragma unroll
    for (int mi = 0; mi < 4; ++mi)
#pragma unroll
      for (int nj = 0; nj < 2; ++nj) {
        acc1[mi][nj] = __builtin_amdgcn_mfma_f32_16x16x32_bf16(af[mi], bf1[nj], acc1[mi][nj], 0, 0, 0);
        acc3[mi][nj] = __builtin_amdgcn_mfma_f32_16x16x32_bf16(af[mi], bf3[nj], acc3[mi][nj], 0, 0, 0);
      }
    __syncthreads();
    a0 += 32; a1 += 32; b1p += 32; b3p += 32;
  }

  // epilogue: hidden = silu(acc1)*acc3, bf16 store
  // C/D layout: col = lane&15, row = quad*4 + reg  [verified m89/m91]
  ushort_t* hb = hidden + ((size_t)e * CAP + mt * 128) * FDIM + nt * 64;
#pragma unroll
  for (int mi = 0; mi < 4; ++mi)
#pragma unroll
    for (int nj = 0; nj < 2; ++nj)
#pragma unroll
      for (int r = 0; r < 4; ++r) {
        int row = wm * 64 + mi * 16 + quad * 4 + r;
        int col = wn * 32 + nj * 16 + l15;
        float v1 = acc1[mi][nj][r];
        float v3 = acc3[mi][nj][r];
        float s = (v1 / (1.f + __expf(-v1))) * v3;
        hb[(size_t)row * FDIM + col] = f2b(s);
      }
}

// ------------------------------------- GEMM2: hidden @ w2 -> weighted scatter-add
// split-K = 2 (free: epilogue is already atomicAdd, weight scaling is linear)
__global__ void __launch_bounds__(256) gemm2_scatter_k(
    const ushort_t* __restrict__ hidden, // [E][CAP][FDIM]
    const ushort_t* __restrict__ w2t,    // [E][HDIM][FDIM]
    const int* __restrict__ idx,
    const float* __restrict__ wgt,
    float* __restrict__ y)               // [T_TOK][HDIM]
{
  // b = ((e*2 + kk)*10 + mt)*8 + nt
  int b = blockIdx.x;
  int nt = b & 7; int t1 = b >> 3; int mt = t1 % 10; int t2 = t1 / 10;
  int kk = t2 & 1; int e = t2 >> 1;

  __shared__ __bf16 Alds[128 * 32];
  __shared__ __bf16 Blds[128 * 32];
  __shared__ int   idxs[128];
  __shared__ float wgts[128];

  int tid = threadIdx.x;
  int lane = tid & 63, wave = tid >> 6;
  int wm = wave & 1, wn = wave >> 1;
  int l15 = lane & 15, quad = lane >> 4;

  if (tid < 128) {
    idxs[tid] = idx[e * CAP + mt * 128 + tid];
    wgts[tid] = wgt[e * CAP + mt * 128 + tid];
  }

  int r0 = tid >> 2, kc0 = tid & 3;
  int r1 = r0 + 64;
  size_t kof = (size_t)kk * (FDIM / 2);
  const ushort_t* a0 = hidden + ((size_t)e * CAP + mt * 128 + r0) * FDIM + kof + kc0 * 8;
  const ushort_t* a1 = hidden + ((size_t)e * CAP + mt * 128 + r1) * FDIM + kof + kc0 * 8;
  const ushort_t* b0 = w2t + ((size_t)e * HDIM + nt * 128 + r0) * FDIM + kof + kc0 * 8;
  const ushort_t* b1 = w2t + ((size_t)e * HDIM + nt * 128 + r1) * FDIM + kof + kc0 * 8;

  f32x4 acc[4][4];
#pragma unroll
  for (int i = 0; i < 4; ++i)
#pragma unroll
    for (int j = 0; j < 4; ++j) acc[i][j] = (f32x4){0.f, 0.f, 0.f, 0.f};

  for (int kt = 0; kt < (FDIM / 2) / 32; ++kt) {
    gl_lds16(a0, Alds + (size_t)tid * 8);
    gl_lds16(a1, Alds + (size_t)(tid + 256) * 8);
    gl_lds16(b0, Blds + (size_t)tid * 8);
    gl_lds16(b1, Blds + (size_t)(tid + 256) * 8);
    __syncthreads();

    bf16x8 af[4], bf[4];
#pragma unroll
    for (int i = 0; i < 4; ++i) {
      af[i] = *(const bf16x8*)(Alds + ((wm * 64 + i * 16 + l15) * 32 + quad * 8));
      bf[i] = *(const bf16x8*)(Blds + ((wn * 64 + i * 16 + l15) * 32 + quad * 8));
    }
#pragma unroll
    for (int mi = 0; mi < 4; ++mi)
#pragma unroll
      for (int nj = 0; nj < 4; ++nj)
        acc[mi][nj] = __builtin_amdgcn_mfma_f32_16x16x32_bf16(af[mi], bf[nj], acc[mi][nj], 0, 0, 0);
    __syncthreads();
    a0 += 32; a1 += 32; b0 += 32; b1 += 32;
  }

#pragma unroll
  for (int mi = 0; mi < 4; ++mi)
#pragma unroll
    for (int nj = 0; nj < 4; ++nj)
#pragma unroll
      for (int r = 0; r < 4; ++r) {
        int row = wm * 64 + mi * 16 + quad * 4 + r;
        int col = nt * 128 + wn * 64 + nj * 16 + l15;
        float v = acc[mi][nj][r] * wgts[row];
        atomicAdd(y + (size_t)idxs[row] * HDIM + col, v);
      }
}

// --------------------------------------------------------------------- launch
extern "C" void kernel_launch(void* const* d_in, const int* in_sizes, int n_in,
                              void* d_out, int out_size, void* d_ws, size_t ws_size,
                              hipStream_t stream)
{
  const float* x  = (const float*)d_in[0];
  const float* gw = (const float*)d_in[1];
  const float* w1 = (const float*)d_in[2];
  const float* w2 = (const float*)d_in[3];
  const float* w3 = (const float*)d_in[4];
  float* y = (float*)d_out;

  char* ws = (char*)d_ws;
  float*    logits = (float*)(ws + 0x0);           // 256 KB
  int*      idx    = (int*)(ws + 0x40000);         // 40 KB
  float*    wgt    = (float*)(ws + 0x4A000);       // 40 KB
  ushort_t* xb     = (ushort_t*)(ws + 0x54000);    // 16 MB  [T][H] bf16
  ushort_t* w1t    = (ushort_t*)(ws + 0x1054000);  // 32 MB  [E][F][H]
  ushort_t* w3t    = (ushort_t*)(ws + 0x3054000);  // 32 MB
  ushort_t* w2t    = (ushort_t*)(ws + 0x5054000);  // 32 MB  [E][H][F]
  ushort_t* hid    = (ushort_t*)(ws + 0x7054000);  // 40 MB  [E][CAP][F]

  hipMemsetAsync(d_out, 0, (size_t)out_size * sizeof(float), stream);
  gate_logits_k<<<T_TOK / 4, 256, 0, stream>>>(x, gw, logits);
  topk_softmax_k<<<EXP, 1024, 0, stream>>>(logits, idx, wgt);
  cast_bf16_k<<<T_TOK * HDIM / (256 * 8), 256, 0, stream>>>(x, xb);
  transpose_cast_k<<<EXP * (HDIM / 64) * (FDIM / 64), 256, 0, stream>>>(w1, w1t, HDIM, FDIM);
  transpose_cast_k<<<EXP * (HDIM / 64) * (FDIM / 64), 256, 0, stream>>>(w3, w3t, HDIM, FDIM);
  transpose_cast_k<<<EXP * (FDIM / 64) * (HDIM / 64), 256, 0, stream>>>(w2, w2t, FDIM, HDIM);
  gemm1_swiglu_k<<<EXP * 4 * 10 * 8, 256, 0, stream>>>(xb, w1t, w3t, idx, hid);
  gemm2_scatter_k<<<EXP * 2 * 10 * 8, 256, 0, stream>>>(hid, w2t, idx, wgt, y);
}